// Round 3
// baseline (108.259 us; speedup 1.0000x reference)
//
#include <hip/hip_runtime.h>

// Pipeline: k0 W-transpose -> k1 QKV GEMM (LDS-staged, 1 barrier) -> k2 attention.
// fp16 MFMA 16x16x32: A row=lane&15,k=8*(lane>>4)+i; B col=lane&15,k=8*(lane>>4)+i;
//                     C/D col=lane&15, row=4*(lane>>4)+reg.
// A-frag and B-frag share the same lane mapping -> one x fragment register is
// used as A for Q/K (D[t][n]) and as B for V with Wv^T as A (D[h][t]).

#define B_ 256
#define T_ 256
#define C_ 384
#define H_ 64

typedef __attribute__((ext_vector_type(4))) float     f32x4;
typedef __attribute__((ext_vector_type(8))) _Float16  f16x8;
typedef __attribute__((ext_vector_type(4))) _Float16  f16x4;

#define MFMA16(a, b, c) __builtin_amdgcn_mfma_f32_16x16x32_f16((a), (b), (c), 0, 0, 0)

// ---------------- workspace layout (bytes) ----------------
constexpr size_t WT_OFF = 0;                       // [192][384] f16 (q|k|v rows, k-major)
constexpr size_t QH_OFF = 147456;                  // [65536][64] f16, pre-scaled
constexpr size_t KH_OFF = QH_OFF + 8388608;        // [65536][64] f16
constexpr size_t VT_OFF = KH_OFF + 8388608;        // [256][64][256] f16 (V^T per batch)
constexpr size_t WS_NEED = VT_OFF + 8388608;       // 25,313,280 B

// ================= k0: W -> Wt (cast+transpose) =================
__global__ void w_transpose(const float* __restrict__ Wq,
                            const float* __restrict__ Wk,
                            const float* __restrict__ Wv,
                            _Float16* __restrict__ Wt) {
    int e = blockIdx.x * 256 + threadIdx.x;      // 0..73727
    int h = e & 63;
    int k = (e >> 6) % 384;
    int p = e / 24576;
    const float* W = (p == 0) ? Wq : (p == 1) ? Wk : Wv;
    Wt[(size_t)(p * 64 + h) * 384 + k] = (_Float16)W[k * 64 + h];
}

// ================= k1: QKV = x @ [Wq|Wk|Wv] =================
// 1024 blocks x 256 threads (4 waves). BM=64 rows, full K=384 in one swizzled
// LDS tile (48 KB). One barrier. Wave w owns t-rows [16w,16w+16).
__global__ __launch_bounds__(256, 3) void qkv_gemm(
    const float* __restrict__ x, const _Float16* __restrict__ Wt,
    _Float16* __restrict__ Qh, _Float16* __restrict__ Kh,
    _Float16* __restrict__ Vt)
{
    __shared__ _Float16 xs[64 * 384];            // swizzled: 16B-group g = c8 ^ (row&7)

    const int tid = threadIdx.x, lane = tid & 63, w = tid >> 6;
    const int lo = lane & 15, hi = lane >> 4;
    const int blk = blockIdx.x;
    const float* xb = x + (size_t)blk * 64 * C_;

    // ---- stage x[64][384] fp32 -> fp16 LDS, coalesced (12 x 32B per thread) ----
    #pragma unroll
    for (int i = 0; i < 12; ++i) {
        int chunk = tid + i * 256;               // 0..3071 : 16B fp16 chunks
        int row   = chunk / 48;                  // 48 chunks per row (384 halfs)
        int c8    = chunk - row * 48;            // k-group of 8
        const float* gp = xb + row * C_ + c8 * 8;
        float4 u = *(const float4*)gp;
        float4 v = *(const float4*)(gp + 4);
        f16x8 hv = {(_Float16)u.x, (_Float16)u.y, (_Float16)u.z, (_Float16)u.w,
                    (_Float16)v.x, (_Float16)v.y, (_Float16)v.z, (_Float16)v.w};
        int g = c8 ^ (row & 7);
        *(f16x8*)(xs + row * 384 + g * 8) = hv;
    }
    __syncthreads();

    // ---- compute: per kk one x-frag read, 12 W-frags (L1), 12 MFMAs ----
    f32x4 aq[8] = {};                            // nt 0-3: Q cols, nt 4-7: K cols
    f32x4 av[4] = {};                            // ht 0-3: V^T rows (h)
    const int xrow = 16 * w + lo;
    const int xr7  = xrow & 7;
    #pragma unroll
    for (int kk = 0; kk < 12; ++kk) {
        f16x8 xf = *(const f16x8*)(xs + xrow * 384 + ((kk * 4 + hi) ^ xr7) * 8);
        #pragma unroll
        for (int nt = 0; nt < 8; ++nt) {
            f16x8 wf = *(const f16x8*)(Wt + (size_t)(16 * nt + lo) * C_ + kk * 32 + 8 * hi);
            aq[nt] = MFMA16(xf, wf, aq[nt]);
        }
        #pragma unroll
        for (int ht = 0; ht < 4; ++ht) {
            f16x8 wv = *(const f16x8*)(Wt + (size_t)(128 + 16 * ht + lo) * C_ + kk * 32 + 8 * hi);
            av[ht] = MFMA16(wv, xf, av[ht]);
        }
    }

    // ---- epilogue ----
    const int tq = blk * 64 + 16 * w + 4 * hi;   // + reg : global t for Q/K rows
    #pragma unroll
    for (int nt = 0; nt < 4; ++nt)
        #pragma unroll
        for (int reg = 0; reg < 4; ++reg)
            Qh[(size_t)(tq + reg) * 64 + 16 * nt + lo] = (_Float16)(0.125f * aq[nt][reg]);
    #pragma unroll
    for (int nt = 4; nt < 8; ++nt)
        #pragma unroll
        for (int reg = 0; reg < 4; ++reg)
            Kh[(size_t)(tq + reg) * 64 + 16 * (nt - 4) + lo] = (_Float16)aq[nt][reg];

    const int b  = blk >> 2;
    const int tl = (blk & 3) * 64 + 16 * w + lo; // within-batch t (V^T column)
    #pragma unroll
    for (int ht = 0; ht < 4; ++ht)
        #pragma unroll
        for (int reg = 0; reg < 4; ++reg)
            Vt[(size_t)b * 16384 + (size_t)(16 * ht + 4 * hi + reg) * 256 + tl]
                = (_Float16)av[ht][reg];
}

// ================= k2: attention per batch =================
// 256 blocks x 512 threads (8 indep waves, 32 q-rows each). LDS only for P-bounce.
constexpr int SP = 72;

__global__ __launch_bounds__(512, 2) void attn(
    const _Float16* __restrict__ Qh, const _Float16* __restrict__ Kh,
    const _Float16* __restrict__ Vt, float* __restrict__ out)
{
    __shared__ _Float16 Ps[8 * 32 * SP];
    const int tid = threadIdx.x, lane = tid & 63, wid = tid >> 6;
    const int lo = lane & 15, hi = lane >> 4;
    const int b = blockIdx.x;
    const int ctmax = 2 * wid + 1;               // last S column-tile with valid entries

    // Q fragments (own 32 rows)
    f16x8 aq[2][2];
    #pragma unroll
    for (int rt = 0; rt < 2; ++rt)
        #pragma unroll
        for (int ks = 0; ks < 2; ++ks)
            aq[rt][ks] = *(const f16x8*)(Qh + (size_t)(b * 256 + 32 * wid + 16 * rt + lo) * 64
                                         + 32 * ks + 8 * hi);

    // S = Q K^T (skip fully-masked column tiles)
    f32x4 sacc[2][16] = {};
    #pragma unroll
    for (int ct = 0; ct < 16; ++ct) {
        if (ct <= ctmax) {
            #pragma unroll
            for (int ks = 0; ks < 2; ++ks) {
                f16x8 bk = *(const f16x8*)(Kh + (size_t)(b * 256 + 16 * ct + lo) * 64
                                           + 32 * ks + 8 * hi);
                sacc[0][ct] = MFMA16(aq[0][ks], bk, sacc[0][ct]);
                sacc[1][ct] = MFMA16(aq[1][ks], bk, sacc[1][ct]);
            }
        }
    }

    // causal mask + softmax (row across 16-lane group)
    #pragma unroll
    for (int rt = 0; rt < 2; ++rt) {
        #pragma unroll
        for (int reg = 0; reg < 4; ++reg) {
            const int rowg = 32 * wid + 16 * rt + 4 * hi + reg;
            float m = -1e30f;
            #pragma unroll
            for (int ct = 0; ct < 16; ++ct) if (ct <= ctmax) {
                float v = sacc[rt][ct][reg];
                v = (16 * ct + lo <= rowg) ? v : -1e30f;
                sacc[rt][ct][reg] = v;
                m = fmaxf(m, v);
            }
            #pragma unroll
            for (int s = 1; s < 16; s <<= 1) m = fmaxf(m, __shfl_xor(m, s, 16));
            float l = 0.f;
            #pragma unroll
            for (int ct = 0; ct < 16; ++ct) if (ct <= ctmax) {
                float v = sacc[rt][ct][reg];
                float p = (v > -1e29f) ? __expf(v - m) : 0.f;
                sacc[rt][ct][reg] = p;
                l += p;
            }
            #pragma unroll
            for (int s = 1; s < 16; s <<= 1) l += __shfl_xor(l, s, 16);
            float rinv = 1.f / l;
            #pragma unroll
            for (int ct = 0; ct < 16; ++ct) if (ct <= ctmax) sacc[rt][ct][reg] *= rinv;
        }
    }

    // O = P V (bounce P through per-wave LDS chunk; V^T fragments from L2)
    f32x4 oacc[2][4] = {};
    _Float16* Pw = Ps + wid * 32 * SP;
    const int kcmax = ctmax >> 2;
    #pragma unroll
    for (int kc = 0; kc < 4; ++kc) {
        if (kc <= kcmax) {
            #pragma unroll
            for (int rt = 0; rt < 2; ++rt)
                #pragma unroll
                for (int c = 0; c < 4; ++c) {
                    const int ct = 4 * kc + c;
                    #pragma unroll
                    for (int reg = 0; reg < 4; ++reg) {
                        float v = (ct <= ctmax) ? sacc[rt][ct][reg] : 0.f;
                        Pw[(16 * rt + 4 * hi + reg) * SP + c * 16 + lo] = (_Float16)v;
                    }
                }
            asm volatile("s_waitcnt lgkmcnt(0)" ::: "memory");
            #pragma unroll
            for (int ks = 0; ks < 2; ++ks) {
                f16x8 a0 = *(const f16x8*)(Pw + lo * SP + 32 * ks + 8 * hi);
                f16x8 a1 = *(const f16x8*)(Pw + (16 + lo) * SP + 32 * ks + 8 * hi);
                #pragma unroll
                for (int ht = 0; ht < 4; ++ht) {
                    f16x8 bv = *(const f16x8*)(Vt + (size_t)b * 16384 + (size_t)(16 * ht + lo) * 256
                                               + 64 * kc + 32 * ks + 8 * hi);
                    oacc[0][ht] = MFMA16(a0, bv, oacc[0][ht]);
                    oacc[1][ht] = MFMA16(a1, bv, oacc[1][ht]);
                }
            }
            asm volatile("s_waitcnt lgkmcnt(0)" ::: "memory");
        }
    }

    float* ob = out + (size_t)b * (T_ * H_);
    #pragma unroll
    for (int rt = 0; rt < 2; ++rt)
        #pragma unroll
        for (int ht = 0; ht < 4; ++ht)
            #pragma unroll
            for (int reg = 0; reg < 4; ++reg) {
                const int t = 32 * wid + 16 * rt + 4 * hi + reg;
                ob[t * H_ + 16 * ht + lo] = oacc[rt][ht][reg];
            }
}

extern "C" void kernel_launch(void* const* d_in, const int* in_sizes, int n_in,
                              void* d_out, int out_size, void* d_ws, size_t ws_size,
                              hipStream_t stream) {
    const float* x  = (const float*)d_in[0];
    const float* Wq = (const float*)d_in[1];
    const float* Wk = (const float*)d_in[2];
    const float* Wv = (const float*)d_in[3];
    float* out = (float*)d_out;
    (void)in_sizes; (void)n_in; (void)out_size; (void)ws_size;

    char* ws = (char*)d_ws;
    _Float16* Wt = (_Float16*)(ws + WT_OFF);
    _Float16* Qh = (_Float16*)(ws + QH_OFF);
    _Float16* Kh = (_Float16*)(ws + KH_OFF);
    _Float16* Vt = (_Float16*)(ws + VT_OFF);

    w_transpose<<<dim3(288), dim3(256), 0, stream>>>(Wq, Wk, Wv, Wt);
    qkv_gemm<<<dim3(1024), dim3(256), 0, stream>>>(x, Wt, Qh, Kh, Vt);
    attn<<<dim3(B_), dim3(512), 0, stream>>>(Qh, Kh, Vt, out);
}

// Round 4
// 78.434 us; speedup vs baseline: 1.3803x; 1.3803x over previous
//
#include <hip/hip_runtime.h>

// Pipeline: k0 W-transpose -> k1 QKV GEMM (32x32 MFMA, reg-resident W) -> k2 attention.
// fp16 MFMA 32x32x16: A row=lane&31,k=8*(lane>>5)+i; B col=lane&31,k=8*(lane>>5)+i;
//                     C/D col=lane&31, row=(reg&3)+8*(reg>>2)+4*(lane>>5).
// fp16 MFMA 16x16x32 (attn): A row=lane&15; B col=lane&15; C/D col=lane&15,row=4*(lane>>4)+reg.

#define B_ 256
#define T_ 256
#define C_ 384
#define H_ 64

typedef __attribute__((ext_vector_type(4)))  float     f32x4;
typedef __attribute__((ext_vector_type(16))) float     f32x16;
typedef __attribute__((ext_vector_type(8)))  _Float16  f16x8;
typedef __attribute__((ext_vector_type(4)))  _Float16  f16x4;

#define MFMA16(a, b, c) __builtin_amdgcn_mfma_f32_16x16x32_f16((a), (b), (c), 0, 0, 0)
#define MFMA32(a, b, c) __builtin_amdgcn_mfma_f32_32x32x16_f16((a), (b), (c), 0, 0, 0)

// ---------------- workspace layout (bytes) ----------------
constexpr size_t WT_OFF = 0;                       // [192][384] f16 (q|k|v rows, k-major)
constexpr size_t QH_OFF = 147456;                  // [65536][64] f16, pre-scaled
constexpr size_t KH_OFF = QH_OFF + 8388608;        // [65536][64] f16
constexpr size_t VT_OFF = KH_OFF + 8388608;        // [256][64][256] f16 (V^T per batch)
constexpr size_t WS_NEED = VT_OFF + 8388608;       // 25,313,280 B

// ================= k0: W -> Wt (cast+transpose) =================
__global__ void w_transpose(const float* __restrict__ Wq,
                            const float* __restrict__ Wk,
                            const float* __restrict__ Wv,
                            _Float16* __restrict__ Wt) {
    int e = blockIdx.x * 256 + threadIdx.x;      // 0..73727
    int h = e & 63;
    int k = (e >> 6) % 384;
    int p = e / 24576;
    const float* W = (p == 0) ? Wq : (p == 1) ? Wk : Wv;
    Wt[(size_t)(p * 64 + h) * 384 + k] = (_Float16)W[k * 64 + h];
}

// ================= k1: QKV = x @ [Wq|Wk|Wv] =================
// 1024 blocks x 384 threads (6 waves). BM=64 rows, full K=384 in one swizzled
// LDS tile. Wave w: 0,1 -> Q cols 32w.., 2,3 -> K, 4,5 -> V. W in registers
// (12 frags per phase), inner loop = ds_read + MFMA only.
__global__ __launch_bounds__(384, 4) void qkv_gemm(
    const float* __restrict__ x, const _Float16* __restrict__ Wt,
    _Float16* __restrict__ Qh, _Float16* __restrict__ Kh,
    _Float16* __restrict__ Vt)
{
    __shared__ _Float16 xs[64 * 384];            // swizzled: 16B-group g = c8 ^ (row&7)

    const int tid = threadIdx.x, lane = tid & 63, w = tid >> 6;
    const int l31 = lane & 31, hi2 = lane >> 5;
    const int blk = blockIdx.x;
    const float* xb = x + (size_t)blk * 64 * C_;

    // ---- stage x[64][384] fp32 -> fp16 LDS, coalesced ----
    #pragma unroll
    for (int i = 0; i < 8; ++i) {
        int chunk = tid + i * 384;               // 0..3071 : 16B fp16 chunks
        int row   = chunk / 48;
        int c8    = chunk - row * 48;
        const float* gp = xb + row * C_ + c8 * 8;
        float4 u = *(const float4*)gp;
        float4 v = *(const float4*)(gp + 4);
        f16x8 hv = {(_Float16)u.x, (_Float16)u.y, (_Float16)u.z, (_Float16)u.w,
                    (_Float16)v.x, (_Float16)v.y, (_Float16)v.z, (_Float16)v.w};
        int g = c8 ^ (row & 7);
        *(f16x8*)(xs + row * 384 + g * 8) = hv;
    }
    __syncthreads();

    const bool isV  = (w >= 4);
    const int  wtrow = (isV ? 128 + (w - 4) * 32 : w * 32) + l31;
    const _Float16* wp = Wt + (size_t)wtrow * C_ + 8 * hi2;

    f32x16 acc0 = {}, acc1 = {};
    const int r0 = l31, r1 = 32 + l31;
    const int s7 = l31 & 7;                      // row&7 (same for r0, r1)

    if (!isV) {
        #pragma unroll
        for (int ph = 0; ph < 2; ++ph) {
            f16x8 wreg[12];
            #pragma unroll
            for (int j = 0; j < 12; ++j)
                wreg[j] = *(const f16x8*)(wp + (ph * 12 + j) * 16);
            #pragma unroll
            for (int j = 0; j < 12; ++j) {
                int kk = ph * 12 + j;
                f16x8 xf0 = *(const f16x8*)(xs + r0 * 384 + ((kk * 2 + hi2) ^ s7) * 8);
                f16x8 xf1 = *(const f16x8*)(xs + r1 * 384 + ((kk * 2 + hi2) ^ s7) * 8);
                acc0 = MFMA32(xf0, wreg[j], acc0);   // D[t][n]
                acc1 = MFMA32(xf1, wreg[j], acc1);
            }
        }
    } else {
        #pragma unroll
        for (int ph = 0; ph < 2; ++ph) {
            f16x8 wreg[12];
            #pragma unroll
            for (int j = 0; j < 12; ++j)
                wreg[j] = *(const f16x8*)(wp + (ph * 12 + j) * 16);
            #pragma unroll
            for (int j = 0; j < 12; ++j) {
                int kk = ph * 12 + j;
                f16x8 xf0 = *(const f16x8*)(xs + r0 * 384 + ((kk * 2 + hi2) ^ s7) * 8);
                f16x8 xf1 = *(const f16x8*)(xs + r1 * 384 + ((kk * 2 + hi2) ^ s7) * 8);
                acc0 = MFMA32(wreg[j], xf0, acc0);   // D[h][t]
                acc1 = MFMA32(wreg[j], xf1, acc1);
            }
        }
    }

    // ---- epilogue ----
    if (!isV) {
        _Float16* dst = (w < 2) ? Qh : Kh;
        const float scale = (w < 2) ? 0.125f : 1.0f;
        const int n = (w & 1) * 32 + l31;
        #pragma unroll
        for (int rt = 0; rt < 2; ++rt) {
            const f32x16& a = rt ? acc1 : acc0;
            #pragma unroll
            for (int reg = 0; reg < 16; ++reg) {
                int row = (reg & 3) + 8 * (reg >> 2) + 4 * hi2;
                int t = blk * 64 + rt * 32 + row;
                dst[(size_t)t * 64 + n] = (_Float16)(scale * a[reg]);
            }
        }
    } else {
        const int b = blk >> 2, tbase = (blk & 3) * 64;
        #pragma unroll
        for (int rt = 0; rt < 2; ++rt) {
            const f32x16& a = rt ? acc1 : acc0;
            #pragma unroll
            for (int reg = 0; reg < 16; ++reg) {
                int h  = (w - 4) * 32 + (reg & 3) + 8 * (reg >> 2) + 4 * hi2;
                int tl = tbase + rt * 32 + l31;
                Vt[(size_t)b * 16384 + (size_t)h * 256 + tl] = (_Float16)a[reg];
            }
        }
    }
}

// ================= k2: attention per batch =================
// 256 blocks x 512 threads (8 indep waves, 32 q-rows each). LDS only for P-bounce.
constexpr int SP = 72;

__global__ __launch_bounds__(512, 2) void attn(
    const _Float16* __restrict__ Qh, const _Float16* __restrict__ Kh,
    const _Float16* __restrict__ Vt, float* __restrict__ out)
{
    __shared__ _Float16 Ps[8 * 32 * SP];
    const int tid = threadIdx.x, lane = tid & 63, wid = tid >> 6;
    const int lo = lane & 15, hi = lane >> 4;
    const int b = blockIdx.x;
    const int ctmax = 2 * wid + 1;               // last S column-tile with valid entries

    // Q fragments (own 32 rows)
    f16x8 aq[2][2];
    #pragma unroll
    for (int rt = 0; rt < 2; ++rt)
        #pragma unroll
        for (int ks = 0; ks < 2; ++ks)
            aq[rt][ks] = *(const f16x8*)(Qh + (size_t)(b * 256 + 32 * wid + 16 * rt + lo) * 64
                                         + 32 * ks + 8 * hi);

    // S = Q K^T (skip fully-masked column tiles)
    f32x4 sacc[2][16] = {};
    #pragma unroll
    for (int ct = 0; ct < 16; ++ct) {
        if (ct <= ctmax) {
            #pragma unroll
            for (int ks = 0; ks < 2; ++ks) {
                f16x8 bk = *(const f16x8*)(Kh + (size_t)(b * 256 + 16 * ct + lo) * 64
                                           + 32 * ks + 8 * hi);
                sacc[0][ct] = MFMA16(aq[0][ks], bk, sacc[0][ct]);
                sacc[1][ct] = MFMA16(aq[1][ks], bk, sacc[1][ct]);
            }
        }
    }

    // causal mask + softmax (row across 16-lane group)
    #pragma unroll
    for (int rt = 0; rt < 2; ++rt) {
        #pragma unroll
        for (int reg = 0; reg < 4; ++reg) {
            const int rowg = 32 * wid + 16 * rt + 4 * hi + reg;
            float m = -1e30f;
            #pragma unroll
            for (int ct = 0; ct < 16; ++ct) if (ct <= ctmax) {
                float v = sacc[rt][ct][reg];
                v = (16 * ct + lo <= rowg) ? v : -1e30f;
                sacc[rt][ct][reg] = v;
                m = fmaxf(m, v);
            }
            #pragma unroll
            for (int s = 1; s < 16; s <<= 1) m = fmaxf(m, __shfl_xor(m, s, 16));
            float l = 0.f;
            #pragma unroll
            for (int ct = 0; ct < 16; ++ct) if (ct <= ctmax) {
                float v = sacc[rt][ct][reg];
                float p = (v > -1e29f) ? __expf(v - m) : 0.f;
                sacc[rt][ct][reg] = p;
                l += p;
            }
            #pragma unroll
            for (int s = 1; s < 16; s <<= 1) l += __shfl_xor(l, s, 16);
            float rinv = 1.f / l;
            #pragma unroll
            for (int ct = 0; ct < 16; ++ct) if (ct <= ctmax) sacc[rt][ct][reg] *= rinv;
        }
    }

    // O = P V (bounce P through per-wave LDS chunk; V^T fragments from L2)
    f32x4 oacc[2][4] = {};
    _Float16* Pw = Ps + wid * 32 * SP;
    const int kcmax = ctmax >> 2;
    #pragma unroll
    for (int kc = 0; kc < 4; ++kc) {
        if (kc <= kcmax) {
            #pragma unroll
            for (int rt = 0; rt < 2; ++rt)
                #pragma unroll
                for (int c = 0; c < 4; ++c) {
                    const int ct = 4 * kc + c;
                    #pragma unroll
                    for (int reg = 0; reg < 4; ++reg) {
                        float v = (ct <= ctmax) ? sacc[rt][ct][reg] : 0.f;
                        Pw[(16 * rt + 4 * hi + reg) * SP + c * 16 + lo] = (_Float16)v;
                    }
                }
            asm volatile("s_waitcnt lgkmcnt(0)" ::: "memory");
            #pragma unroll
            for (int ks = 0; ks < 2; ++ks) {
                f16x8 a0 = *(const f16x8*)(Pw + lo * SP + 32 * ks + 8 * hi);
                f16x8 a1 = *(const f16x8*)(Pw + (16 + lo) * SP + 32 * ks + 8 * hi);
                #pragma unroll
                for (int ht = 0; ht < 4; ++ht) {
                    f16x8 bv = *(const f16x8*)(Vt + (size_t)b * 16384 + (size_t)(16 * ht + lo) * 256
                                               + 64 * kc + 32 * ks + 8 * hi);
                    oacc[0][ht] = MFMA16(a0, bv, oacc[0][ht]);
                    oacc[1][ht] = MFMA16(a1, bv, oacc[1][ht]);
                }
            }
            asm volatile("s_waitcnt lgkmcnt(0)" ::: "memory");
        }
    }

    float* ob = out + (size_t)b * (T_ * H_);
    #pragma unroll
    for (int rt = 0; rt < 2; ++rt)
        #pragma unroll
        for (int ht = 0; ht < 4; ++ht)
            #pragma unroll
            for (int reg = 0; reg < 4; ++reg) {
                const int t = 32 * wid + 16 * rt + 4 * hi + reg;
                ob[t * H_ + 16 * ht + lo] = oacc[rt][ht][reg];
            }
}

extern "C" void kernel_launch(void* const* d_in, const int* in_sizes, int n_in,
                              void* d_out, int out_size, void* d_ws, size_t ws_size,
                              hipStream_t stream) {
    const float* x  = (const float*)d_in[0];
    const float* Wq = (const float*)d_in[1];
    const float* Wk = (const float*)d_in[2];
    const float* Wv = (const float*)d_in[3];
    float* out = (float*)d_out;
    (void)in_sizes; (void)n_in; (void)out_size; (void)ws_size;

    char* ws = (char*)d_ws;
    _Float16* Wt = (_Float16*)(ws + WT_OFF);
    _Float16* Qh = (_Float16*)(ws + QH_OFF);
    _Float16* Kh = (_Float16*)(ws + KH_OFF);
    _Float16* Vt = (_Float16*)(ws + VT_OFF);

    w_transpose<<<dim3(288), dim3(256), 0, stream>>>(Wq, Wk, Wv, Wt);
    qkv_gemm<<<dim3(1024), dim3(384), 0, stream>>>(x, Wt, Qh, Kh, Vt);
    attn<<<dim3(B_), dim3(512), 0, stream>>>(Qh, Kh, Vt, out);
}

// Round 5
// 63.182 us; speedup vs baseline: 1.7135x; 1.2414x over previous
//
#include <hip/hip_runtime.h>

// Pipeline: k0 W->fragment-coalesced Wf -> k1 QKV GEMM (32x32 MFMA, coalesced W,
// LDS-repacked epilogue) -> k2 attention.
// fp16 MFMA 32x32x16: A row=lane&31,k=8*(lane>>5)+i; B col=lane&31,k=8*(lane>>5)+i;
//                     C/D col=lane&31, row=(reg&3)+8*(reg>>2)+4*(lane>>5).
// fp16 MFMA 16x16x32 (attn): A row=lane&15; B col=lane&15; C/D col=lane&15,row=4*(lane>>4)+reg.

#define B_ 256
#define T_ 256
#define C_ 384
#define H_ 64

typedef __attribute__((ext_vector_type(4)))  float     f32x4;
typedef __attribute__((ext_vector_type(16))) float     f32x16;
typedef __attribute__((ext_vector_type(8)))  _Float16  f16x8;

#define MFMA16(a, b, c) __builtin_amdgcn_mfma_f32_16x16x32_f16((a), (b), (c), 0, 0, 0)
#define MFMA32(a, b, c) __builtin_amdgcn_mfma_f32_32x32x16_f16((a), (b), (c), 0, 0, 0)

// ---------------- workspace layout (bytes) ----------------
// Wf: fragment-coalesced W: for col-group g(0..5: Q0 Q1 K0 K1 V0 V1), k-chunk
// kk(0..23), the 64 lanes' f16x8 frags stored contiguously (1KB per (g,kk)).
constexpr size_t WF_OFF = 0;                       // 192*384*2 = 147456 B
constexpr size_t QH_OFF = 147456;                  // [65536][64] f16, pre-scaled
constexpr size_t KH_OFF = QH_OFF + 8388608;        // [65536][64] f16
constexpr size_t VT_OFF = KH_OFF + 8388608;        // [256][64][256] f16 (V^T per batch)

// ================= k0: W -> Wf (cast + fragment layout) =================
__global__ void w_fragpack(const float* __restrict__ Wq,
                           const float* __restrict__ Wk,
                           const float* __restrict__ Wv,
                           _Float16* __restrict__ Wf) {
    int e = blockIdx.x * 256 + threadIdx.x;      // 0..73727
    int i   = e & 7;
    int l31 = (e >> 3) & 31;
    int hi2 = (e >> 8) & 1;
    int cid = e >> 9;                             // g*24 + kk
    int kk  = cid % 24;
    int g   = cid / 24;
    int col = g * 32 + l31;                       // 0..191 in [Q|K|V]
    int p   = col >> 6;
    int h   = col & 63;
    int k   = kk * 16 + hi2 * 8 + i;
    const float* W = (p == 0) ? Wq : (p == 1) ? Wk : Wv;
    Wf[e] = (_Float16)W[k * 64 + h];
}

// ================= k1: QKV = x @ [Wq|Wk|Wv] =================
// 1024 blocks x 384 threads (6 waves). BM=64 rows, full K=384 in one swizzled
// LDS tile (48KB). Wave g: 0,1 -> Q cols, 2,3 -> K, 4,5 -> V (W as A-operand).
// W-frag loads are contiguous 1KB per (g,kk). Epilogue repacks through LDS for
// full-line global stores.
__global__ __launch_bounds__(384, 4) void qkv_gemm(
    const float* __restrict__ x, const _Float16* __restrict__ Wf,
    _Float16* __restrict__ Qh, _Float16* __restrict__ Kh,
    _Float16* __restrict__ Vt)
{
    __shared__ _Float16 xs[64 * 384];            // swizzled: 16B-group g = c8 ^ (row&7)

    const int tid = threadIdx.x, lane = tid & 63, w = tid >> 6;
    const int l31 = lane & 31, hi2 = lane >> 5;
    const int blk = blockIdx.x;
    const float* xb = x + (size_t)blk * 64 * C_;

    // ---- stage x[64][384] fp32 -> fp16 LDS, coalesced ----
    #pragma unroll
    for (int i = 0; i < 8; ++i) {
        int chunk = tid + i * 384;               // 0..3071 : 16B fp16 chunks
        int row   = chunk / 48;
        int c8    = chunk - row * 48;
        const float* gp = xb + row * C_ + c8 * 8;
        float4 u = *(const float4*)gp;
        float4 v = *(const float4*)(gp + 4);
        f16x8 hv = {(_Float16)u.x, (_Float16)u.y, (_Float16)u.z, (_Float16)u.w,
                    (_Float16)v.x, (_Float16)v.y, (_Float16)v.z, (_Float16)v.w};
        int g = c8 ^ (row & 7);
        *(f16x8*)(xs + row * 384 + g * 8) = hv;
    }
    __syncthreads();

    const bool isV = (w >= 4);
    const _Float16* wbase = Wf + (size_t)(w * 24) * 512 + lane * 8;

    f32x16 acc0 = {}, acc1 = {};
    const int r0 = l31, r1 = 32 + l31;
    const int s7 = l31 & 7;

    #pragma unroll
    for (int ph = 0; ph < 2; ++ph) {
        f16x8 wreg[12];
        #pragma unroll
        for (int j = 0; j < 12; ++j)
            wreg[j] = *(const f16x8*)(wbase + (ph * 12 + j) * 512);
        #pragma unroll
        for (int j = 0; j < 12; ++j) {
            int kk = ph * 12 + j;
            f16x8 xf0 = *(const f16x8*)(xs + r0 * 384 + ((kk * 2 + hi2) ^ s7) * 8);
            f16x8 xf1 = *(const f16x8*)(xs + r1 * 384 + ((kk * 2 + hi2) ^ s7) * 8);
            if (!isV) {
                acc0 = MFMA32(xf0, wreg[j], acc0);   // D[t][n]
                acc1 = MFMA32(xf1, wreg[j], acc1);
            } else {
                acc0 = MFMA32(wreg[j], xf0, acc0);   // D[h][t]
                acc1 = MFMA32(wreg[j], xf1, acc1);
            }
        }
    }

    // ---- epilogue: repack through LDS, then full-line global stores ----
    __syncthreads();                              // xs free now
    // regions (halfs): Q [64t][64n] @0, K @4096, V [64h][64t] @8192
    {
        const float scale = (w < 2) ? 0.125f : 1.0f;
        #pragma unroll
        for (int rt = 0; rt < 2; ++rt) {
            const f32x16& a = rt ? acc1 : acc0;
            #pragma unroll
            for (int reg = 0; reg < 16; ++reg) {
                int rr = rt * 32 + (reg & 3) + 8 * (reg >> 2) + 4 * hi2;
                if (!isV) {
                    // Q waves: w=0,1 ; K waves: w=2,3
                    int region = (w < 2) ? 0 : 4096;
                    int n = (w & 1) * 32 + l31;
                    xs[region + rr * 64 + n] = (_Float16)(scale * a[reg]);
                } else {
                    int h = (w - 4) * 32 + (reg & 3) + 8 * (reg >> 2) + 4 * hi2;
                    int tl = rt * 32 + l31;
                    xs[8192 + h * 64 + tl] = (_Float16)a[reg];
                }
            }
        }
    }
    __syncthreads();

    const int b = blk >> 2, tbase = (blk & 3) * 64;
    #pragma unroll
    for (int i = 0; i < 4; ++i) {
        int c = tid + i * 384;                    // 0..1535 : 16B chunks
        f16x8 v = *(const f16x8*)(xs + c * 8);
        if (c < 512) {
            int tl = c >> 3, n8 = c & 7;
            *(f16x8*)(Qh + (size_t)(blk * 64 + tl) * 64 + n8 * 8) = v;
        } else if (c < 1024) {
            int c2 = c - 512, tl = c2 >> 3, n8 = c2 & 7;
            *(f16x8*)(Kh + (size_t)(blk * 64 + tl) * 64 + n8 * 8) = v;
        } else {
            int c3 = c - 1024, h = c3 >> 3, t8 = c3 & 7;
            *(f16x8*)(Vt + (size_t)b * 16384 + (size_t)h * 256 + tbase + t8 * 8) = v;
        }
    }
}

// ================= k2: attention per batch =================
// 256 blocks x 512 threads (8 indep waves, 32 q-rows each). LDS only for P-bounce.
constexpr int SP = 72;

__global__ __launch_bounds__(512, 2) void attn(
    const _Float16* __restrict__ Qh, const _Float16* __restrict__ Kh,
    const _Float16* __restrict__ Vt, float* __restrict__ out)
{
    __shared__ _Float16 Ps[8 * 32 * SP];
    const int tid = threadIdx.x, lane = tid & 63, wid = tid >> 6;
    const int lo = lane & 15, hi = lane >> 4;
    const int b = blockIdx.x;
    const int ctmax = 2 * wid + 1;               // last S column-tile with valid entries

    f16x8 aq[2][2];
    #pragma unroll
    for (int rt = 0; rt < 2; ++rt)
        #pragma unroll
        for (int ks = 0; ks < 2; ++ks)
            aq[rt][ks] = *(const f16x8*)(Qh + (size_t)(b * 256 + 32 * wid + 16 * rt + lo) * 64
                                         + 32 * ks + 8 * hi);

    f32x4 sacc[2][16] = {};
    #pragma unroll
    for (int ct = 0; ct < 16; ++ct) {
        if (ct <= ctmax) {
            #pragma unroll
            for (int ks = 0; ks < 2; ++ks) {
                f16x8 bk = *(const f16x8*)(Kh + (size_t)(b * 256 + 16 * ct + lo) * 64
                                           + 32 * ks + 8 * hi);
                sacc[0][ct] = MFMA16(aq[0][ks], bk, sacc[0][ct]);
                sacc[1][ct] = MFMA16(aq[1][ks], bk, sacc[1][ct]);
            }
        }
    }

    #pragma unroll
    for (int rt = 0; rt < 2; ++rt) {
        #pragma unroll
        for (int reg = 0; reg < 4; ++reg) {
            const int rowg = 32 * wid + 16 * rt + 4 * hi + reg;
            float m = -1e30f;
            #pragma unroll
            for (int ct = 0; ct < 16; ++ct) if (ct <= ctmax) {
                float v = sacc[rt][ct][reg];
                v = (16 * ct + lo <= rowg) ? v : -1e30f;
                sacc[rt][ct][reg] = v;
                m = fmaxf(m, v);
            }
            #pragma unroll
            for (int s = 1; s < 16; s <<= 1) m = fmaxf(m, __shfl_xor(m, s, 16));
            float l = 0.f;
            #pragma unroll
            for (int ct = 0; ct < 16; ++ct) if (ct <= ctmax) {
                float v = sacc[rt][ct][reg];
                float p = (v > -1e29f) ? __expf(v - m) : 0.f;
                sacc[rt][ct][reg] = p;
                l += p;
            }
            #pragma unroll
            for (int s = 1; s < 16; s <<= 1) l += __shfl_xor(l, s, 16);
            float rinv = 1.f / l;
            #pragma unroll
            for (int ct = 0; ct < 16; ++ct) if (ct <= ctmax) sacc[rt][ct][reg] *= rinv;
        }
    }

    f32x4 oacc[2][4] = {};
    _Float16* Pw = Ps + wid * 32 * SP;
    const int kcmax = ctmax >> 2;
    #pragma unroll
    for (int kc = 0; kc < 4; ++kc) {
        if (kc <= kcmax) {
            #pragma unroll
            for (int rt = 0; rt < 2; ++rt)
                #pragma unroll
                for (int c = 0; c < 4; ++c) {
                    const int ct = 4 * kc + c;
                    #pragma unroll
                    for (int reg = 0; reg < 4; ++reg) {
                        float v = (ct <= ctmax) ? sacc[rt][ct][reg] : 0.f;
                        Pw[(16 * rt + 4 * hi + reg) * SP + c * 16 + lo] = (_Float16)v;
                    }
                }
            asm volatile("s_waitcnt lgkmcnt(0)" ::: "memory");
            #pragma unroll
            for (int ks = 0; ks < 2; ++ks) {
                f16x8 a0 = *(const f16x8*)(Pw + lo * SP + 32 * ks + 8 * hi);
                f16x8 a1 = *(const f16x8*)(Pw + (16 + lo) * SP + 32 * ks + 8 * hi);
                #pragma unroll
                for (int ht = 0; ht < 4; ++ht) {
                    f16x8 bv = *(const f16x8*)(Vt + (size_t)b * 16384 + (size_t)(16 * ht + lo) * 256
                                               + 64 * kc + 32 * ks + 8 * hi);
                    oacc[0][ht] = MFMA16(a0, bv, oacc[0][ht]);
                    oacc[1][ht] = MFMA16(a1, bv, oacc[1][ht]);
                }
            }
            asm volatile("s_waitcnt lgkmcnt(0)" ::: "memory");
        }
    }

    float* ob = out + (size_t)b * (T_ * H_);
    #pragma unroll
    for (int rt = 0; rt < 2; ++rt)
        #pragma unroll
        for (int ht = 0; ht < 4; ++ht)
            #pragma unroll
            for (int reg = 0; reg < 4; ++reg) {
                const int t = 32 * wid + 16 * rt + 4 * hi + reg;
                ob[t * H_ + 16 * ht + lo] = oacc[rt][ht][reg];
            }
}

extern "C" void kernel_launch(void* const* d_in, const int* in_sizes, int n_in,
                              void* d_out, int out_size, void* d_ws, size_t ws_size,
                              hipStream_t stream) {
    const float* x  = (const float*)d_in[0];
    const float* Wq = (const float*)d_in[1];
    const float* Wk = (const float*)d_in[2];
    const float* Wv = (const float*)d_in[3];
    float* out = (float*)d_out;
    (void)in_sizes; (void)n_in; (void)out_size; (void)ws_size;

    char* ws = (char*)d_ws;
    _Float16* Wf = (_Float16*)(ws + WF_OFF);
    _Float16* Qh = (_Float16*)(ws + QH_OFF);
    _Float16* Kh = (_Float16*)(ws + KH_OFF);
    _Float16* Vt = (_Float16*)(ws + VT_OFF);

    w_fragpack<<<dim3(288), dim3(256), 0, stream>>>(Wq, Wk, Wv, Wf);
    qkv_gemm<<<dim3(1024), dim3(384), 0, stream>>>(x, Wf, Qh, Kh, Vt);
    attn<<<dim3(B_), dim3(512), 0, stream>>>(Qh, Kh, Vt, out);
}